// Round 17
// baseline (301.178 us; speedup 1.0000x reference)
//
#include <hip/hip_runtime.h>
#include <cstddef>

typedef unsigned short u16;
typedef unsigned int   u32;
typedef __bf16 bf16_t;
typedef bf16_t bf16x8 __attribute__((ext_vector_type(8)));
typedef short  s16x4  __attribute__((ext_vector_type(4)));
typedef float  f32x4  __attribute__((ext_vector_type(4)));
typedef u16    u16x4  __attribute__((ext_vector_type(4)));

// ---- constants ----
// B=1 S=14 H=56 W=56 C=192 WS=7 SH=3 HEADS=6 HD=32 N=343 NW=128 L=43904
#define NPAD 352   // padded tokens (22*16)
#define VTS  352   // Vt row stride in u16
#define LOG2E 1.4426950408889634f
#define RESCALE_THR 11.5f   // log2 units (~8 nats); P <= 2^11.5, bf16-safe

__device__ __forceinline__ u16 f2b(float f) {
  return __builtin_bit_cast(u16, (__bf16)f);
}
__device__ __forceinline__ float b2f(u16 h) {
  return __uint_as_float(((u32)h) << 16);
}
__device__ __forceinline__ float fexp2(float x) {
#if __has_builtin(__builtin_amdgcn_exp2f)
  return __builtin_amdgcn_exp2f(x);
#else
  float r; asm("v_exp_f32 %0, %1" : "=v"(r) : "v"(x)); return r;
#endif
}
__device__ __forceinline__ f32x4 mfma16(bf16x8 a, bf16x8 b, f32x4 c) {
  return __builtin_amdgcn_mfma_f32_16x16x32_bf16(a, b, c, 0, 0, 0);
}
__device__ __forceinline__ f32x4 mfma16x16(s16x4 a, s16x4 b, f32x4 c) {
#if __has_builtin(__builtin_amdgcn_mfma_f32_16x16x16bf16_1k)
  return __builtin_amdgcn_mfma_f32_16x16x16bf16_1k(a, b, c, 0, 0, 0);
#else
  f32x4 d;
  asm volatile("v_mfma_f32_16x16x16_bf16 %0, %1, %2, %3"
               : "=&v"(d) : "v"(a), "v"(b), "v"(c));
  return d;
#endif
}
__device__ __forceinline__ void gl_lds16(const void* g, void* l) {
  __builtin_amdgcn_global_load_lds((const __attribute__((address_space(1))) void*)g,
                                   (__attribute__((address_space(3))) void*)l, 16, 0, 0);
}

// windowed (w, n) -> global token index (applies the -SH roll: g = r + 3 mod dims)
__device__ __forceinline__ int win_to_global(int w, int n) {
  int ws = w >> 6, wh = (w >> 3) & 7, ww = w & 7;
  int ts = (n * 1338) >> 16;          // n/49  (valid n<2520)
  int rem = n - ts * 49;
  int th = (rem * 9363) >> 16;        // rem/7 (valid <13107)
  int tw = rem - th * 7;
  int gs = ws * 7 + ts + 3; if (gs >= 14) gs -= 14;
  int gh = wh * 7 + th + 3; if (gh >= 56) gh -= 56;
  int gw = ww * 7 + tw + 3; if (gw >= 56) gw -= 56;
  return (gs * 56 + gh) * 56 + gw;
}

// ================== fused pre-pass: maskconv | ln1 | wconv | bias ==================
// NOTE: mask and bias are pre-scaled by LOG2E; Q is pre-scaled by SCALE*LOG2E, so the
// attention softmax runs entirely in the exp2 domain (one v_exp_f32 per element).
#define MC_END 15488
#define LN_END (MC_END + 10976)
#define WC_END (LN_END + 1824)
#define PRE_GRID (WC_END + 726)

__global__ __launch_bounds__(256) void k_pre(
    const float* __restrict__ mask, u16* __restrict__ mb,
    const float* __restrict__ skip, const float* __restrict__ xup,
    const float* __restrict__ g1, const float* __restrict__ b1,
    u16* __restrict__ skw, u16* __restrict__ qb,
    const float* __restrict__ kv_w, const float* __restrict__ proj_w,
    const float* __restrict__ fc1_w, const float* __restrict__ fc2_w,
    u16* kvT, u16* projT, u16* fc1T, u16* fc2T,
    const float* __restrict__ tbl, u16* __restrict__ bf) {
  int bid = blockIdx.x, tid = threadIdx.x;
  if (bid < MC_END) {
    // ---- mask f32 [128][343][343] -> bf16*LOG2E [128][352][352] padded ----
    int t = bid * 256 + tid;
    int w = t / (352 * 88);
    int r = t - w * (352 * 88);
    int n = r / 88;
    int q = r - n * 88;
    u16x4 v = {0, 0, 0, 0};
    if (n < 343) {
      const float* src = mask + ((size_t)w * 343 + n) * 343 + q * 4;
      #pragma unroll
      for (int j = 0; j < 4; ++j) if (q * 4 + j < 343) v[j] = f2b(src[j] * LOG2E);
    }
    *(u16x4*)&mb[((size_t)w * 352 + n) * 352 + q * 4] = v;
  } else if (bid < LN_END) {
    // ---- LN1 + shift-roll + partition: skip -> skw, x_up -> q (*SCALE*LOG2E) ----
    int wid = tid >> 6, lane = tid & 63;
    int m = (bid - MC_END) * 4 + wid;
    u32 w = ((u32)m * 48914u) >> 24;
    int n = m - (int)w * 343;
    int g = win_to_global((int)w, n);
    float xs[3], xu[3];
    float s1 = 0.f, s2 = 0.f, t1 = 0.f, t2 = 0.f;
    #pragma unroll
    for (int i = 0; i < 3; ++i) {
      int c = lane + i * 64;
      xs[i] = skip[(size_t)g * 192 + c];
      xu[i] = xup[(size_t)g * 192 + c];
      s1 += xs[i]; s2 += xs[i] * xs[i];
      t1 += xu[i]; t2 += xu[i] * xu[i];
    }
    #pragma unroll
    for (int off = 1; off < 64; off <<= 1) {
      s1 += __shfl_xor(s1, off); s2 += __shfl_xor(s2, off);
      t1 += __shfl_xor(t1, off); t2 += __shfl_xor(t2, off);
    }
    const float inv = 1.f / 192.f;
    float ms = s1 * inv, vs = s2 * inv - ms * ms;
    float mu = t1 * inv, vu = t2 * inv - mu * mu;
    float rs = rsqrtf(vs + 1e-5f), ru = rsqrtf(vu + 1e-5f);
    #pragma unroll
    for (int i = 0; i < 3; ++i) {
      int c = lane + i * 64;
      float gg = g1[c], bb = b1[c];
      skw[(size_t)m * 192 + c] = f2b((xs[i] - ms) * rs * gg + bb);
      float qv = ((xu[i] - mu) * ru * gg + bb) * 0.25503513f; // HD^-0.5 * LOG2E
      int h = c >> 5, d = c & 31;
      qb[(size_t)(((int)w * 6 + h) * NPAD + n) * 32 + d] = f2b(qv);
    }
  } else if (bid < WC_END) {
    // ---- weight convert f32 (K,N) -> bf16 (N,K) ----
    int t = (bid - LN_END) * 256 + tid;
    if (t < 384 * 192) { int nn = t / 192, kk = t - nn * 192; kvT[t] = f2b(kv_w[kk * 384 + nn]); return; }
    t -= 384 * 192;
    if (t < 256 * 192) { int nn = t / 192, kk = t - nn * 192; projT[t] = (nn < 192) ? f2b(proj_w[kk * 192 + nn]) : (u16)0; return; }
    t -= 256 * 192;
    if (t < 768 * 192) { int nn = t / 192, kk = t - nn * 192; fc1T[t] = f2b(fc1_w[kk * 768 + nn]); return; }
    t -= 768 * 192;
    if (t < 256 * 768) { int nn = t / 768, kk = t - nn * 768; fc2T[t] = (nn < 192) ? f2b(fc2_w[kk * 192 + nn]) : (u16)0; return; }
  } else {
    // ---- dense rel-pos bias * LOG2E, vec4: bf[h][n][m] (352x352, pad=0) ----
    int t = (bid - WC_END) * 256 + tid;   // t < 6*352*88
    int h = t / (352 * 88);
    int r = t - h * (352 * 88);
    int n = r / 88;
    int q = r - n * 88;
    u16x4 v = {0, 0, 0, 0};
    if (n < 343 && h < 6) {
      int tsn = (n * 1338) >> 16, remn = n - tsn * 49, thn = (remn * 9363) >> 16, twn = remn - thn * 7;
      #pragma unroll
      for (int j = 0; j < 4; ++j) {
        int m = q * 4 + j;
        if (m < 343) {
          int tsm = (m * 1338) >> 16, remm = m - tsm * 49, thm = (remm * 9363) >> 16, twm = remm - thm * 7;
          int idx = (thn - thm) * 20 + (tsn - tsm) * 13 + (twn - twm) + 204;
          v[j] = f2b(tbl[idx * 6 + h] * LOG2E);
        }
      }
    }
    if (h < 6) *(u16x4*)&bf[((size_t)h * 352 + n) * 352 + q * 4] = v;
  }
}

// ---- LN2: xres f32 -> bf16 ----
__global__ __launch_bounds__(256) void k_ln2(const float* __restrict__ xr,
    const float* __restrict__ g2, const float* __restrict__ b2, u16* __restrict__ o) {
  int wid = threadIdx.x >> 6, lane = threadIdx.x & 63;
  int m = blockIdx.x * 4 + wid;
  float v[3]; float s1 = 0.f, s2 = 0.f;
  #pragma unroll
  for (int i = 0; i < 3; ++i) {
    int c = lane + i * 64;
    v[i] = xr[(size_t)m * 192 + c];
    s1 += v[i]; s2 += v[i] * v[i];
  }
  #pragma unroll
  for (int off = 1; off < 64; off <<= 1) { s1 += __shfl_xor(s1, off); s2 += __shfl_xor(s2, off); }
  const float inv = 1.f / 192.f;
  float ms = s1 * inv, vs = s2 * inv - ms * ms;
  float rs = rsqrtf(vs + 1e-5f);
  #pragma unroll
  for (int i = 0; i < 3; ++i) {
    int c = lane + i * 64;
    o[(size_t)m * 192 + c] = f2b((v[i] - ms) * rs * g2[c] + b2[c]);
  }
}

// ---- generic 128x128 MFMA GEMM, BK=64, A[M][K] bf16 row-major, B[N][K] (pre-transposed).
// LDS [128][64] u16 with 16B-chunk XOR swizzle (sub ^= row&7) applied on BOTH the
// global_load_lds SOURCE address and the ds_read offset (rule #21: LDS dest stays linear).
template<int EPI>
__global__ __launch_bounds__(256) void k_gemm(
    const u16* __restrict__ A, const u16* __restrict__ Bm, int K, int nbn,
    const float* __restrict__ bias,
    u16* __restrict__ outa, u16* __restrict__ outb,
    const float* __restrict__ xin, float* __restrict__ xres,
    float* __restrict__ outf) {
  __shared__ __align__(16) u16 As[128 * 64];
  __shared__ __align__(16) u16 Bs[128 * 64];
  int bid = blockIdx.x;
  int xcd = bid & 7, j = bid >> 3;
  int bn = j % nbn, bmL = j / nbn;
  int bm = xcd * 43 + bmL;
  if (bm >= 343) return;
  int tid = threadIdx.x;
  int wid = tid >> 6, lane = tid & 63, lr = lane & 15, lg = lane >> 4;
  int wr = wid >> 1, wc = wid & 1;
  f32x4 acc[4][4] = {};
  const u16* Abase = A + (size_t)bm * 128 * K;
  const u16* Bbase = Bm + (size_t)bn * 128 * K;
  int nk = K >> 6;                       // K divisible by 64 (192, 768)
  int rsw = lr & 7;                      // row&7 for all this lane's fragment rows
  for (int kt = 0; kt < nk; ++kt) {
    #pragma unroll
    for (int it = 0; it < 4; ++it) {
      int c = it * 256 + tid;            // chunk 0..1023; row = c>>3, sub = c&7
      int row = c >> 3, subp = c & 7;
      int gsub = subp ^ (row & 7);       // inverse-swizzled global source chunk
      gl_lds16(Abase + (size_t)row * K + kt * 64 + gsub * 8, &As[c * 8]);
      gl_lds16(Bbase + (size_t)row * K + kt * 64 + gsub * 8, &Bs[c * 8]);
    }
    __syncthreads();
    #pragma unroll
    for (int kk = 0; kk < 2; ++kk) {
      bf16x8 af[4], bfr[4];
      #pragma unroll
      for (int mi = 0; mi < 4; ++mi)
        af[mi] = *(const bf16x8*)&As[(wr * 64 + mi * 16 + lr) * 64 + ((kk * 4 + lg) ^ rsw) * 8];
      #pragma unroll
      for (int ni = 0; ni < 4; ++ni)
        bfr[ni] = *(const bf16x8*)&Bs[(wc * 64 + ni * 16 + lr) * 64 + ((kk * 4 + lg) ^ rsw) * 8];
      #pragma unroll
      for (int mi = 0; mi < 4; ++mi)
        #pragma unroll
        for (int ni = 0; ni < 4; ++ni)
          acc[mi][ni] = mfma16(af[mi], bfr[ni], acc[mi][ni]);
    }
    __syncthreads();
  }
  #pragma unroll
  for (int mi = 0; mi < 4; ++mi) {
    #pragma unroll
    for (int r = 0; r < 4; ++r) {
      int grow = bm * 128 + wr * 64 + mi * 16 + lg * 4 + r;
      if (EPI == 0) {
        u32 w = ((u32)grow * 48914u) >> 24; int n = grow - (int)w * 343;
        #pragma unroll
        for (int ni = 0; ni < 4; ++ni) {
          int gcol = bn * 128 + wc * 64 + ni * 16 + lr;
          float v = acc[mi][ni][r] + bias[gcol];
          if (gcol < 192) {
            int hh = gcol >> 5, d = gcol & 31;
            int dswz = ((((d >> 3) ^ ((n >> 1) & 3)) << 3) | (d & 7));
            outa[(size_t)(((int)w * 6 + hh) * NPAD + n) * 32 + dswz] = f2b(v);
          } else {
            int c2 = gcol - 192; int hh = c2 >> 5, d = c2 & 31;
            int nswz = ((((n >> 3) ^ ((d >> 1) & 3)) << 3) | (n & 7));
            outb[(size_t)(((int)w * 6 + hh) * 32 + d) * VTS + nswz] = f2b(v);
          }
        }
      } else if (EPI == 1) {
        #pragma unroll
        for (int ni = 0; ni < 4; ++ni) {
          int gcol = bn * 128 + wc * 64 + ni * 16 + lr;
          if (gcol < 192) {
            float v = acc[mi][ni][r] + bias[gcol] + xin[(size_t)grow * 192 + gcol];
            xres[(size_t)grow * 192 + gcol] = v;
          }
        }
      } else if (EPI == 2) {
        #pragma unroll
        for (int ni = 0; ni < 4; ++ni) {
          int gcol = bn * 128 + wc * 64 + ni * 16 + lr;
          float v = acc[mi][ni][r] + bias[gcol];
          v = 0.5f * v * (1.f + erff(v * 0.7071067811865476f));
          outa[(size_t)grow * 768 + gcol] = f2b(v);
        }
      } else {
        #pragma unroll
        for (int ni = 0; ni < 4; ++ni) {
          int gcol = bn * 128 + wc * 64 + ni * 16 + lr;
          if (gcol < 192)
            outf[(size_t)grow * 192 + gcol] = acc[mi][ni][r] + bias[gcol] + xin[(size_t)grow * 192 + gcol];
        }
      }
    }
  }
}

// ---- single-chain attention chunk (used only for leftover query tile 21) ----
template<int CT0, int LEN, bool TAIL, bool FIRST>
__device__ __forceinline__ void attn_chunk(const u16* __restrict__ Ks, const u16* __restrict__ Vs,
    bf16x8 qa, int lr, int lg, int swz,
    const u16* __restrict__ brow, const u16* __restrict__ mrow,
    f32x4& o0, f32x4& o1, float& mrun, float& sum) {
  u16x4 bb[LEN], mm[LEN];
  #pragma unroll
  for (int j = 0; j < LEN; ++j) {
    bb[j] = *(const u16x4*)&brow[(CT0 + j) * 16];
    mm[j] = *(const u16x4*)&mrow[(CT0 + j) * 16];
  }
  f32x4 s[LEN];
  const f32x4 z = {0.f, 0.f, 0.f, 0.f};
  __builtin_amdgcn_s_setprio(1);
  #pragma unroll
  for (int j = 0; j < LEN; ++j) {
    bf16x8 kf = *(const bf16x8*)&Ks[((CT0 + j) * 16 + lr) * 32 + (lg ^ swz) * 8];
    s[j] = mfma16(kf, qa, z);
  }
  __builtin_amdgcn_s_setprio(0);
  #pragma unroll
  for (int j = 0; j < LEN; ++j)
    #pragma unroll
    for (int r = 0; r < 4; ++r) s[j][r] += b2f(bb[j][r]) + b2f(mm[j][r]);
  if (TAIL) {
    int m0 = 336 + lg * 4;
    #pragma unroll
    for (int r = 0; r < 4; ++r) if (m0 + r >= 343) s[LEN - 1][r] = -1e30f;
  }
  float mloc = -1e30f;
  #pragma unroll
  for (int j = 0; j < LEN; ++j)
    mloc = fmaxf(mloc, fmaxf(fmaxf(s[j][0], s[j][1]), fmaxf(s[j][2], s[j][3])));
  if (FIRST) {
    mloc = fmaxf(mloc, __shfl_xor(mloc, 16));
    mloc = fmaxf(mloc, __shfl_xor(mloc, 32));
    mrun = mloc;
  } else if (!__all(mloc <= mrun + RESCALE_THR)) {
    mloc = fmaxf(mloc, __shfl_xor(mloc, 16));
    mloc = fmaxf(mloc, __shfl_xor(mloc, 32));
    float mnew = fmaxf(mrun, mloc);
    float sc = fexp2(mrun - mnew);
    #pragma unroll
    for (int r = 0; r < 4; ++r) {
      float scr = __shfl(sc, lg * 4 + r);
      o0[r] *= scr; o1[r] *= scr;
    }
    sum *= sc;
    mrun = mnew;
  }
  #pragma unroll
  for (int j = 0; j < LEN; ++j)
    #pragma unroll
    for (int r = 0; r < 4; ++r) { float p = fexp2(s[j][r] - mrun); s[j][r] = p; sum += p; }
  __builtin_amdgcn_s_setprio(1);
  #pragma unroll
  for (int j = 0; j < LEN; ++j) {
    s16x4 pa;
    #pragma unroll
    for (int r = 0; r < 4; ++r) pa[r] = (short)f2b(s[j][r]);
    int c16 = 2 * (CT0 + j) + (lg >> 1);
    int vo = ((c16 ^ swz) * 8) + (lg & 1) * 4;
    s16x4 v0 = *(const s16x4*)&Vs[lr * 352 + vo];
    s16x4 v1 = *(const s16x4*)&Vs[(16 + lr) * 352 + vo];
    o0 = mfma16x16(pa, v0, o0);
    o1 = mfma16x16(pa, v1, o1);
  }
  __builtin_amdgcn_s_setprio(0);
}

// THREE-ROW-TILE interleaved attention chunk: chains A/B/C (query tiles 3t,3t+1,3t+2)
// share every K-fragment and V-fragment load; all other state independent. TAIL masks
// the KEY tail (keys 343..351), applied to all chains. Row bookkeeping as before.
template<int CT0, int LEN, bool TAIL, bool FIRST>
__device__ __forceinline__ void attn_chunk3(const u16* __restrict__ Ks, const u16* __restrict__ Vs,
    bf16x8 qaA, bf16x8 qaB, bf16x8 qaC, int lr, int lg, int swz,
    const u16* __restrict__ browA, const u16* __restrict__ mrowA,
    const u16* __restrict__ browB, const u16* __restrict__ mrowB,
    const u16* __restrict__ browC, const u16* __restrict__ mrowC,
    f32x4& o0A, f32x4& o1A, f32x4& o0B, f32x4& o1B, f32x4& o0C, f32x4& o1C,
    float& mrunA, float& mrunB, float& mrunC, float& sumA, float& sumB, float& sumC) {
  u16x4 bbA[LEN], mmA[LEN], bbB[LEN], mmB[LEN], bbC[LEN], mmC[LEN];
  #pragma unroll
  for (int j = 0; j < LEN; ++j) {
    bbA[j] = *(const u16x4*)&browA[(CT0 + j) * 16];
    mmA[j] = *(const u16x4*)&mrowA[(CT0 + j) * 16];
    bbB[j] = *(const u16x4*)&browB[(CT0 + j) * 16];
    mmB[j] = *(const u16x4*)&mrowB[(CT0 + j) * 16];
    bbC[j] = *(const u16x4*)&browC[(CT0 + j) * 16];
    mmC[j] = *(const u16x4*)&mrowC[(CT0 + j) * 16];
  }
  f32x4 sA[LEN], sB[LEN], sC[LEN];
  const f32x4 z = {0.f, 0.f, 0.f, 0.f};
  __builtin_amdgcn_s_setprio(1);
  #pragma unroll
  for (int j = 0; j < LEN; ++j) {
    bf16x8 kf = *(const bf16x8*)&Ks[((CT0 + j) * 16 + lr) * 32 + (lg ^ swz) * 8];
    sA[j] = mfma16(kf, qaA, z);
    sB[j] = mfma16(kf, qaB, z);
    sC[j] = mfma16(kf, qaC, z);
  }
  __builtin_amdgcn_s_setprio(0);
  #pragma unroll
  for (int j = 0; j < LEN; ++j)
    #pragma unroll
    for (int r = 0; r < 4; ++r) {
      sA[j][r] += b2f(bbA[j][r]) + b2f(mmA[j][r]);
      sB[j][r] += b2f(bbB[j][r]) + b2f(mmB[j][r]);
      sC[j][r] += b2f(bbC[j][r]) + b2f(mmC[j][r]);
    }
  if (TAIL) {
    int m0 = 336 + lg * 4;
    #pragma unroll
    for (int r = 0; r < 4; ++r)
      if (m0 + r >= 343) { sA[LEN-1][r] = -1e30f; sB[LEN-1][r] = -1e30f; sC[LEN-1][r] = -1e30f; }
  }
  float mlA = -1e30f, mlB = -1e30f, mlC = -1e30f;
  #pragma unroll
  for (int j = 0; j < LEN; ++j) {
    mlA = fmaxf(mlA, fmaxf(fmaxf(sA[j][0], sA[j][1]), fmaxf(sA[j][2], sA[j][3])));
    mlB = fmaxf(mlB, fmaxf(fmaxf(sB[j][0], sB[j][1]), fmaxf(sB[j][2], sB[j][3])));
    mlC = fmaxf(mlC, fmaxf(fmaxf(sC[j][0], sC[j][1]), fmaxf(sC[j][2], sC[j][3])));
  }
  if (FIRST) {
    mlA = fmaxf(mlA, __shfl_xor(mlA, 16)); mlA = fmaxf(mlA, __shfl_xor(mlA, 32));
    mlB = fmaxf(mlB, __shfl_xor(mlB, 16)); mlB = fmaxf(mlB, __shfl_xor(mlB, 32));
    mlC = fmaxf(mlC, __shfl_xor(mlC, 16)); mlC = fmaxf(mlC, __shfl_xor(mlC, 32));
    mrunA = mlA; mrunB = mlB; mrunC = mlC;
  } else {
    if (!__all(mlA <= mrunA + RESCALE_THR)) {
      mlA = fmaxf(mlA, __shfl_xor(mlA, 16)); mlA = fmaxf(mlA, __shfl_xor(mlA, 32));
      float mnew = fmaxf(mrunA, mlA);
      float sc = fexp2(mrunA - mnew);
      #pragma unroll
      for (int r = 0; r < 4; ++r) {
        float scr = __shfl(sc, lg * 4 + r);
        o0A[r] *= scr; o1A[r] *= scr;
      }
      sumA *= sc; mrunA = mnew;
    }
    if (!__all(mlB <= mrunB + RESCALE_THR)) {
      mlB = fmaxf(mlB, __shfl_xor(mlB, 16)); mlB = fmaxf(mlB, __shfl_xor(mlB, 32));
      float mnew = fmaxf(mrunB, mlB);
      float sc = fexp2(mrunB - mnew);
      #pragma unroll
      for (int r = 0; r < 4; ++r) {
        float scr = __shfl(sc, lg * 4 + r);
        o0B[r] *= scr; o1B[r] *= scr;
      }
      sumB *= sc; mrunB = mnew;
    }
    if (!__all(mlC <= mrunC + RESCALE_THR)) {
      mlC = fmaxf(mlC, __shfl_xor(mlC, 16)); mlC = fmaxf(mlC, __shfl_xor(mlC, 32));
      float mnew = fmaxf(mrunC, mlC);
      float sc = fexp2(mrunC - mnew);
      #pragma unroll
      for (int r = 0; r < 4; ++r) {
        float scr = __shfl(sc, lg * 4 + r);
        o0C[r] *= scr; o1C[r] *= scr;
      }
      sumC *= sc; mrunC = mnew;
    }
  }
  #pragma unroll
  for (int j = 0; j < LEN; ++j)
    #pragma unroll
    for (int r = 0; r < 4; ++r) {
      float pA = fexp2(sA[j][r] - mrunA); sA[j][r] = pA; sumA += pA;
      float pB = fexp2(sB[j][r] - mrunB); sB[j][r] = pB; sumB += pB;
      float pC = fexp2(sC[j][r] - mrunC); sC[j][r] = pC; sumC += pC;
    }
  __builtin_amdgcn_s_setprio(1);
  #pragma unroll
  for (int j = 0; j < LEN; ++j) {
    s16x4 paA, paB, paC;
    #pragma unroll
    for (int r = 0; r < 4; ++r) {
      paA[r] = (short)f2b(sA[j][r]);
      paB[r] = (short)f2b(sB[j][r]);
      paC[r] = (short)f2b(sC[j][r]);
    }
    int c16 = 2 * (CT0 + j) + (lg >> 1);
    int vo = ((c16 ^ swz) * 8) + (lg & 1) * 4;
    s16x4 v0 = *(const s16x4*)&Vs[lr * 352 + vo];
    s16x4 v1 = *(const s16x4*)&Vs[(16 + lr) * 352 + vo];
    o0A = mfma16x16(paA, v0, o0A);
    o1A = mfma16x16(paA, v1, o1A);
    o0B = mfma16x16(paB, v0, o0B);
    o1B = mfma16x16(paB, v1, o1B);
    o0C = mfma16x16(paC, v0, o0C);
    o1C = mfma16x16(paC, v1, o1C);
  }
  __builtin_amdgcn_s_setprio(0);
}

// ---- per-chain finish: reduce sum, row-transposed normalize, Ot transpose, store ----
__device__ __forceinline__ void attn_store(u16* OtW, u16* __restrict__ att,
    int w, int h, int n, int lr, int lg, f32x4 o0, f32x4 o1, float sum, bool guard) {
  sum += __shfl_xor(sum, 16);
  sum += __shfl_xor(sum, 32);
  float rs = 1.f / sum;
  #pragma unroll
  for (int r = 0; r < 4; ++r) {
    float rsr = __shfl(rs, lg * 4 + r);
    OtW[(lg * 4 + r) * 40 + lr] = f2b(o0[r] * rsr);
    OtW[(lg * 4 + r) * 40 + 16 + lr] = f2b(o1[r] * rsr);
  }
  if (!guard || n < 343) {
    int g = win_to_global(w, n);
    bf16x8 ov = *(const bf16x8*)&OtW[lr * 40 + lg * 8];
    *(bf16x8*)&att[(size_t)g * 192 + h * 32 + lg * 8] = ov;
  }
}

// ---- attention: 768 blocks = (xcd, w-local, h); K+V in LDS (chunk-swizzled); QK^T C=0;
//      register-P PV (16x16x16); deferred-max online softmax (exp2 domain); THREE query
//      row-tiles per wave iteration with shared K/V fragments (ILP x3). Triples t=wid+4j
//      (t<=6, tiles 0..20, no query-tail); leftover tile 21 on wave 3 via single-chain
//      path. Uncapped registers (expect ~230, still 2 waves/SIMD; >256 would halve). ----
__global__ __launch_bounds__(256) void k_attn(const u16* __restrict__ qb, const u16* __restrict__ kb,
    const u16* __restrict__ vtb, const u16* __restrict__ bfull, const u16* __restrict__ maskbf,
    u16* __restrict__ att) {
  __shared__ __align__(16) u16 Ks[352 * 32];
  __shared__ __align__(16) u16 Vs[32 * 352];
  __shared__ __align__(16) u16 Ot[4][16 * 40];
  int bid = blockIdx.x;
  int xcd = bid & 7, i = bid >> 3;
  int wl = i / 6, h = i - wl * 6;
  int w = xcd * 16 + wl;
  int tid = threadIdx.x, wid = tid >> 6, lane = tid & 63, lr = lane & 15, lg = lane >> 4;
  const u16* Q  = qb  + (size_t)(w * 6 + h) * NPAD * 32;
  const u16* Kg = kb  + (size_t)(w * 6 + h) * NPAD * 32;
  const u16* Vg = vtb + (size_t)(w * 6 + h) * 32 * VTS;
  const u16* Bp = bfull + (size_t)h * 352 * 352;
  const u16* Mp = maskbf + (size_t)w * 352 * 352;
  #pragma unroll
  for (int it = 0; it < 11; ++it) {
    int idx = it * 256 + tid;
    if (idx < 1408) gl_lds16(Kg + idx * 8, &Ks[idx * 8]);
    else            gl_lds16(Vg + (idx - 1408) * 8, &Vs[(idx - 1408) * 8]);
  }
  __syncthreads();
  int swz = (lr >> 1) & 3;
  u16* OtW = &Ot[wid][0];
  for (int t = wid; t <= 6; t += 4) {
    int nA = (3 * t) * 16 + lr;           // tiles 3t, 3t+1, 3t+2 (max tile 20 -> n<=335)
    int nB = nA + 16;
    int nC = nA + 32;
    bf16x8 qaA = *(const bf16x8*)&Q[(size_t)nA * 32 + lg * 8];
    bf16x8 qaB = *(const bf16x8*)&Q[(size_t)nB * 32 + lg * 8];
    bf16x8 qaC = *(const bf16x8*)&Q[(size_t)nC * 32 + lg * 8];
    const u16* browA = Bp + (size_t)nA * 352 + lg * 4;
    const u16* mrowA = Mp + (size_t)nA * 352 + lg * 4;
    const u16* browB = Bp + (size_t)nB * 352 + lg * 4;
    const u16* mrowB = Mp + (size_t)nB * 352 + lg * 4;
    const u16* browC = Bp + (size_t)nC * 352 + lg * 4;
    const u16* mrowC = Mp + (size_t)nC * 352 + lg * 4;
    f32x4 o0A = {0.f,0.f,0.f,0.f}, o1A = {0.f,0.f,0.f,0.f};
    f32x4 o0B = {0.f,0.f,0.f,0.f}, o1B = {0.f,0.f,0.f,0.f};
    f32x4 o0C = {0.f,0.f,0.f,0.f}, o1C = {0.f,0.f,0.f,0.f};
    float mrunA = -1e30f, mrunB = -1e30f, mrunC = -1e30f;
    float sumA = 0.f, sumB = 0.f, sumC = 0.f;
    attn_chunk3<0,  6, false, true >(Ks, Vs, qaA, qaB, qaC, lr, lg, swz,
        browA, mrowA, browB, mrowB, browC, mrowC,
        o0A, o1A, o0B, o1B, o0C, o1C, mrunA, mrunB, mrunC, sumA, sumB, sumC);
    attn_chunk3<6,  6, false, false>(Ks, Vs, qaA, qaB, qaC, lr, lg, swz,
        browA, mrowA, browB, mrowB, browC, mrowC,
        o0A, o1A, o0B, o1B, o0C, o1C, mrunA, mrunB, mrunC, sumA, sumB, sumC);
    attn_chunk3<12, 6, false, false>(Ks, Vs, qaA, qaB, qaC, lr, lg, swz,
        browA, mrowA, browB, mrowB, browC, mrowC,
        o0A, o1A, o0B, o1B, o0C, o1C, mrunA, mrunB, mrunC, sumA, sumB, sumC);
    attn_chunk3<18, 4, true,  false>(Ks, Vs, qaA, qaB, qaC, lr, lg, swz,
        browA, mrowA, browB, mrowB, browC, mrowC,
        o0A, o1A, o0B, o1B, o0C, o1C, mrunA, mrunB, mrunC, sumA, sumB, sumC);
    attn_store(OtW, att, w, h, nA, lr, lg, o0A, o1A, sumA, false);
    attn_store(OtW, att, w, h, nB, lr, lg, o0B, o1B, sumB, false);
    attn_store(OtW, att, w, h, nC, lr, lg, o0C, o1C, sumC, false);
  }
  if (wid == 3) {   // leftover query tile 21 (rows 336..351; junk rows guarded at store)
    int n = 21 * 16 + lr;
    bf16x8 qa = *(const bf16x8*)&Q[(size_t)n * 32 + lg * 8];
    const u16* brow = Bp + (size_t)n * 352 + lg * 4;
    const u16* mrow = Mp + (size_t)n * 352 + lg * 4;
    f32x4 o0 = {0.f,0.f,0.f,0.f}, o1 = {0.f,0.f,0.f,0.f};
    float mrun = -1e30f, sum = 0.f;
    attn_chunk<0,  6, false, true >(Ks, Vs, qa, lr, lg, swz, brow, mrow, o0, o1, mrun, sum);
    attn_chunk<6,  6, false, false>(Ks, Vs, qa, lr, lg, swz, brow, mrow, o0, o1, mrun, sum);
    attn_chunk<12, 6, false, false>(Ks, Vs, qa, lr, lg, swz, brow, mrow, o0, o1, mrun, sum);
    attn_chunk<18, 4, true,  false>(Ks, Vs, qa, lr, lg, swz, brow, mrow, o0, o1, mrun, sum);
    attn_store(OtW, att, w, h, n, lr, lg, o0, o1, sum, true);
  }
}

// ---- workspace layout (bytes) ----
static const size_t OFF_W    = 0;
static const size_t OFF_XRES = (size_t)1 << 20;            // f32 33.7 MB (shared with maskbf)
static const size_t OFF_MASK = OFF_XRES;                   // bf16 31.7 MB, dead before xres written
static const size_t OFF_LN2  = OFF_XRES + ((size_t)34 << 20);
static const size_t OFF_SKW  = OFF_LN2  + ((size_t)17 << 20);
static const size_t OFF_Q    = OFF_SKW  + ((size_t)17 << 20);
static const size_t OFF_K    = OFF_Q    + ((size_t)17 << 20);
static const size_t OFF_VT   = OFF_K    + ((size_t)17 << 20);
static const size_t OFF_ATT  = OFF_VT   + ((size_t)17 << 20);
static const size_t OFF_BIAS = OFF_ATT  + ((size_t)17 << 20);
static const size_t OFF_FC1  = OFF_SKW;

extern "C" void kernel_launch(void* const* d_in, const int* in_sizes, int n_in,
                              void* d_out, int out_size, void* d_ws, size_t ws_size,
                              hipStream_t stream) {
  const float* x      = (const float*)d_in[0];
  const float* mask   = (const float*)d_in[1];
  const float* skip   = (const float*)d_in[2];
  const float* xup    = (const float*)d_in[3];
  const float* n1g    = (const float*)d_in[4];
  const float* n1b    = (const float*)d_in[5];
  const float* kv_w   = (const float*)d_in[6];
  const float* kv_b   = (const float*)d_in[7];
  const float* tbl    = (const float*)d_in[8];
  const float* proj_w = (const float*)d_in[9];
  const float* proj_b = (const float*)d_in[10];
  const float* n2g    = (const float*)d_in[11];
  const float* n2b    = (const float*)d_in[12];
  const float* fc1_w  = (const float*)d_in[13];
  const float* fc1_b  = (const float*)d_in[14];
  const float* fc2_w  = (const float*)d_in[15];
  const float* fc2_b  = (const float*)d_in[16];
  char* ws = (char*)d_ws;
  u16* kvT   = (u16*)(ws + OFF_W);
  u16* projT = kvT + 384 * 192;
  u16* fc1T  = projT + 256 * 192;
  u16* fc2T  = fc1T + 768 * 192;
  float* xres = (float*)(ws + OFF_XRES);
  u16* maskbf = (u16*)(ws + OFF_MASK);
  u16* ln2o  = (u16*)(ws + OFF_LN2);
  u16* skw   = (u16*)(ws + OFF_SKW);
  u16* qb    = (u16*)(ws + OFF_Q);
  u16* kb    = (u16*)(ws + OFF_K);
  u16* vt    = (u16*)(ws + OFF_VT);
  u16* att   = (u16*)(ws + OFF_ATT);
  u16* bfull = (u16*)(ws + OFF_BIAS);
  u16* fc1o  = (u16*)(ws + OFF_FC1);
  float* outp = (float*)d_out;

  k_pre<<<dim3(PRE_GRID), dim3(256), 0, stream>>>(
      mask, maskbf, skip, xup, n1g, n1b, skw, qb,
      kv_w, proj_w, fc1_w, fc2_w, kvT, projT, fc1T, fc2T, tbl, bfull);
  k_gemm<0><<<dim3(8 * 43 * 3), dim3(256), 0, stream>>>(skw, kvT, 192, 3, kv_b, kb, vt, nullptr, nullptr, nullptr);
  k_attn<<<dim3(768), dim3(256), 0, stream>>>(qb, kb, vt, bfull, maskbf, att);
  k_gemm<1><<<dim3(8 * 43 * 2), dim3(256), 0, stream>>>(att, projT, 192, 2, proj_b, nullptr, nullptr, x, xres, nullptr);
  k_ln2<<<dim3(10976), dim3(256), 0, stream>>>(xres, n2g, n2b, ln2o);
  k_gemm<2><<<dim3(8 * 43 * 6), dim3(256), 0, stream>>>(ln2o, fc1T, 192, 6, fc1_b, fc1o, nullptr, nullptr, nullptr, nullptr);
  k_gemm<3><<<dim3(8 * 43 * 2), dim3(256), 0, stream>>>(fc1o, fc2T, 768, 2, fc2_b, nullptr, nullptr, xres, nullptr, outp);
}

// Round 18
// 291.296 us; speedup vs baseline: 1.0339x; 1.0339x over previous
//
#include <hip/hip_runtime.h>
#include <cstddef>

typedef unsigned short u16;
typedef unsigned int   u32;
typedef __bf16 bf16_t;
typedef bf16_t bf16x8 __attribute__((ext_vector_type(8)));
typedef short  s16x4  __attribute__((ext_vector_type(4)));
typedef float  f32x4  __attribute__((ext_vector_type(4)));
typedef u16    u16x4  __attribute__((ext_vector_type(4)));

// ---- constants ----
// B=1 S=14 H=56 W=56 C=192 WS=7 SH=3 HEADS=6 HD=32 N=343 NW=128 L=43904
#define NPAD 352   // padded tokens (22*16)
#define VTS  352   // Vt row stride in u16
#define LOG2E 1.4426950408889634f
#define RESCALE_THR 11.5f   // log2 units (~8 nats); P <= 2^11.5, bf16-safe

__device__ __forceinline__ u16 f2b(float f) {
  return __builtin_bit_cast(u16, (__bf16)f);
}
__device__ __forceinline__ float b2f(u16 h) {
  return __uint_as_float(((u32)h) << 16);
}
__device__ __forceinline__ float fexp2(float x) {
#if __has_builtin(__builtin_amdgcn_exp2f)
  return __builtin_amdgcn_exp2f(x);
#else
  float r; asm("v_exp_f32 %0, %1" : "=v"(r) : "v"(x)); return r;
#endif
}
__device__ __forceinline__ f32x4 mfma16(bf16x8 a, bf16x8 b, f32x4 c) {
  return __builtin_amdgcn_mfma_f32_16x16x32_bf16(a, b, c, 0, 0, 0);
}
__device__ __forceinline__ f32x4 mfma16x16(s16x4 a, s16x4 b, f32x4 c) {
#if __has_builtin(__builtin_amdgcn_mfma_f32_16x16x16bf16_1k)
  return __builtin_amdgcn_mfma_f32_16x16x16bf16_1k(a, b, c, 0, 0, 0);
#else
  f32x4 d;
  asm volatile("v_mfma_f32_16x16x16_bf16 %0, %1, %2, %3"
               : "=&v"(d) : "v"(a), "v"(b), "v"(c));
  return d;
#endif
}
__device__ __forceinline__ void gl_lds16(const void* g, void* l) {
  __builtin_amdgcn_global_load_lds((const __attribute__((address_space(1))) void*)g,
                                   (__attribute__((address_space(3))) void*)l, 16, 0, 0);
}

// windowed (w, n) -> global token index (applies the -SH roll: g = r + 3 mod dims)
__device__ __forceinline__ int win_to_global(int w, int n) {
  int ws = w >> 6, wh = (w >> 3) & 7, ww = w & 7;
  int ts = (n * 1338) >> 16;          // n/49  (valid n<2520)
  int rem = n - ts * 49;
  int th = (rem * 9363) >> 16;        // rem/7 (valid <13107)
  int tw = rem - th * 7;
  int gs = ws * 7 + ts + 3; if (gs >= 14) gs -= 14;
  int gh = wh * 7 + th + 3; if (gh >= 56) gh -= 56;
  int gw = ww * 7 + tw + 3; if (gw >= 56) gw -= 56;
  return (gs * 56 + gh) * 56 + gw;
}

// ================== fused pre-pass: maskconv | ln1 | wconv | bias ==================
// NOTE: mask and bias are pre-scaled by LOG2E; Q is pre-scaled by SCALE*LOG2E, so the
// attention softmax runs entirely in the exp2 domain (one v_exp_f32 per element).
#define MC_END 15488
#define LN_END (MC_END + 10976)
#define WC_END (LN_END + 1824)
#define PRE_GRID (WC_END + 726)

__global__ __launch_bounds__(256) void k_pre(
    const float* __restrict__ mask, u16* __restrict__ mb,
    const float* __restrict__ skip, const float* __restrict__ xup,
    const float* __restrict__ g1, const float* __restrict__ b1,
    u16* __restrict__ skw, u16* __restrict__ qb,
    const float* __restrict__ kv_w, const float* __restrict__ proj_w,
    const float* __restrict__ fc1_w, const float* __restrict__ fc2_w,
    u16* kvT, u16* projT, u16* fc1T, u16* fc2T,
    const float* __restrict__ tbl, u16* __restrict__ bf) {
  int bid = blockIdx.x, tid = threadIdx.x;
  if (bid < MC_END) {
    // ---- mask f32 [128][343][343] -> bf16*LOG2E [128][352][352] padded ----
    int t = bid * 256 + tid;
    int w = t / (352 * 88);
    int r = t - w * (352 * 88);
    int n = r / 88;
    int q = r - n * 88;
    u16x4 v = {0, 0, 0, 0};
    if (n < 343) {
      const float* src = mask + ((size_t)w * 343 + n) * 343 + q * 4;
      #pragma unroll
      for (int j = 0; j < 4; ++j) if (q * 4 + j < 343) v[j] = f2b(src[j] * LOG2E);
    }
    *(u16x4*)&mb[((size_t)w * 352 + n) * 352 + q * 4] = v;
  } else if (bid < LN_END) {
    // ---- LN1 + shift-roll + partition: skip -> skw, x_up -> q (*SCALE*LOG2E) ----
    int wid = tid >> 6, lane = tid & 63;
    int m = (bid - MC_END) * 4 + wid;
    u32 w = ((u32)m * 48914u) >> 24;
    int n = m - (int)w * 343;
    int g = win_to_global((int)w, n);
    float xs[3], xu[3];
    float s1 = 0.f, s2 = 0.f, t1 = 0.f, t2 = 0.f;
    #pragma unroll
    for (int i = 0; i < 3; ++i) {
      int c = lane + i * 64;
      xs[i] = skip[(size_t)g * 192 + c];
      xu[i] = xup[(size_t)g * 192 + c];
      s1 += xs[i]; s2 += xs[i] * xs[i];
      t1 += xu[i]; t2 += xu[i] * xu[i];
    }
    #pragma unroll
    for (int off = 1; off < 64; off <<= 1) {
      s1 += __shfl_xor(s1, off); s2 += __shfl_xor(s2, off);
      t1 += __shfl_xor(t1, off); t2 += __shfl_xor(t2, off);
    }
    const float inv = 1.f / 192.f;
    float ms = s1 * inv, vs = s2 * inv - ms * ms;
    float mu = t1 * inv, vu = t2 * inv - mu * mu;
    float rs = rsqrtf(vs + 1e-5f), ru = rsqrtf(vu + 1e-5f);
    #pragma unroll
    for (int i = 0; i < 3; ++i) {
      int c = lane + i * 64;
      float gg = g1[c], bb = b1[c];
      skw[(size_t)m * 192 + c] = f2b((xs[i] - ms) * rs * gg + bb);
      float qv = ((xu[i] - mu) * ru * gg + bb) * 0.25503513f; // HD^-0.5 * LOG2E
      int h = c >> 5, d = c & 31;
      qb[(size_t)(((int)w * 6 + h) * NPAD + n) * 32 + d] = f2b(qv);
    }
  } else if (bid < WC_END) {
    // ---- weight convert f32 (K,N) -> bf16 (N,K) ----
    int t = (bid - LN_END) * 256 + tid;
    if (t < 384 * 192) { int nn = t / 192, kk = t - nn * 192; kvT[t] = f2b(kv_w[kk * 384 + nn]); return; }
    t -= 384 * 192;
    if (t < 256 * 192) { int nn = t / 192, kk = t - nn * 192; projT[t] = (nn < 192) ? f2b(proj_w[kk * 192 + nn]) : (u16)0; return; }
    t -= 256 * 192;
    if (t < 768 * 192) { int nn = t / 192, kk = t - nn * 192; fc1T[t] = f2b(fc1_w[kk * 768 + nn]); return; }
    t -= 768 * 192;
    if (t < 256 * 768) { int nn = t / 768, kk = t - nn * 768; fc2T[t] = (nn < 192) ? f2b(fc2_w[kk * 192 + nn]) : (u16)0; return; }
  } else {
    // ---- dense rel-pos bias * LOG2E, vec4: bf[h][n][m] (352x352, pad=0) ----
    int t = (bid - WC_END) * 256 + tid;   // t < 6*352*88
    int h = t / (352 * 88);
    int r = t - h * (352 * 88);
    int n = r / 88;
    int q = r - n * 88;
    u16x4 v = {0, 0, 0, 0};
    if (n < 343 && h < 6) {
      int tsn = (n * 1338) >> 16, remn = n - tsn * 49, thn = (remn * 9363) >> 16, twn = remn - thn * 7;
      #pragma unroll
      for (int j = 0; j < 4; ++j) {
        int m = q * 4 + j;
        if (m < 343) {
          int tsm = (m * 1338) >> 16, remm = m - tsm * 49, thm = (remm * 9363) >> 16, twm = remm - thm * 7;
          int idx = (thn - thm) * 20 + (tsn - tsm) * 13 + (twn - twm) + 204;
          v[j] = f2b(tbl[idx * 6 + h] * LOG2E);
        }
      }
    }
    if (h < 6) *(u16x4*)&bf[((size_t)h * 352 + n) * 352 + q * 4] = v;
  }
}

// ---- LN2: xres f32 -> bf16 ----
__global__ __launch_bounds__(256) void k_ln2(const float* __restrict__ xr,
    const float* __restrict__ g2, const float* __restrict__ b2, u16* __restrict__ o) {
  int wid = threadIdx.x >> 6, lane = threadIdx.x & 63;
  int m = blockIdx.x * 4 + wid;
  float v[3]; float s1 = 0.f, s2 = 0.f;
  #pragma unroll
  for (int i = 0; i < 3; ++i) {
    int c = lane + i * 64;
    v[i] = xr[(size_t)m * 192 + c];
    s1 += v[i]; s2 += v[i] * v[i];
  }
  #pragma unroll
  for (int off = 1; off < 64; off <<= 1) { s1 += __shfl_xor(s1, off); s2 += __shfl_xor(s2, off); }
  const float inv = 1.f / 192.f;
  float ms = s1 * inv, vs = s2 * inv - ms * ms;
  float rs = rsqrtf(vs + 1e-5f);
  #pragma unroll
  for (int i = 0; i < 3; ++i) {
    int c = lane + i * 64;
    o[(size_t)m * 192 + c] = f2b((v[i] - ms) * rs * g2[c] + b2[c]);
  }
}

// ---- generic 128x128 MFMA GEMM, BK=64, A[M][K] bf16 row-major, B[N][K] (pre-transposed).
// LDS [128][64] u16 with 16B-chunk XOR swizzle (sub ^= row&7) applied on BOTH the
// global_load_lds SOURCE address and the ds_read offset (rule #21: LDS dest stays linear).
template<int EPI>
__global__ __launch_bounds__(256) void k_gemm(
    const u16* __restrict__ A, const u16* __restrict__ Bm, int K, int nbn,
    const float* __restrict__ bias,
    u16* __restrict__ outa, u16* __restrict__ outb,
    const float* __restrict__ xin, float* __restrict__ xres,
    float* __restrict__ outf) {
  __shared__ __align__(16) u16 As[128 * 64];
  __shared__ __align__(16) u16 Bs[128 * 64];
  int bid = blockIdx.x;
  int xcd = bid & 7, j = bid >> 3;
  int bn = j % nbn, bmL = j / nbn;
  int bm = xcd * 43 + bmL;
  if (bm >= 343) return;
  int tid = threadIdx.x;
  int wid = tid >> 6, lane = tid & 63, lr = lane & 15, lg = lane >> 4;
  int wr = wid >> 1, wc = wid & 1;
  f32x4 acc[4][4] = {};
  const u16* Abase = A + (size_t)bm * 128 * K;
  const u16* Bbase = Bm + (size_t)bn * 128 * K;
  int nk = K >> 6;                       // K divisible by 64 (192, 768)
  int rsw = lr & 7;                      // row&7 for all this lane's fragment rows
  for (int kt = 0; kt < nk; ++kt) {
    #pragma unroll
    for (int it = 0; it < 4; ++it) {
      int c = it * 256 + tid;            // chunk 0..1023; row = c>>3, sub = c&7
      int row = c >> 3, subp = c & 7;
      int gsub = subp ^ (row & 7);       // inverse-swizzled global source chunk
      gl_lds16(Abase + (size_t)row * K + kt * 64 + gsub * 8, &As[c * 8]);
      gl_lds16(Bbase + (size_t)row * K + kt * 64 + gsub * 8, &Bs[c * 8]);
    }
    __syncthreads();
    #pragma unroll
    for (int kk = 0; kk < 2; ++kk) {
      bf16x8 af[4], bfr[4];
      #pragma unroll
      for (int mi = 0; mi < 4; ++mi)
        af[mi] = *(const bf16x8*)&As[(wr * 64 + mi * 16 + lr) * 64 + ((kk * 4 + lg) ^ rsw) * 8];
      #pragma unroll
      for (int ni = 0; ni < 4; ++ni)
        bfr[ni] = *(const bf16x8*)&Bs[(wc * 64 + ni * 16 + lr) * 64 + ((kk * 4 + lg) ^ rsw) * 8];
      #pragma unroll
      for (int mi = 0; mi < 4; ++mi)
        #pragma unroll
        for (int ni = 0; ni < 4; ++ni)
          acc[mi][ni] = mfma16(af[mi], bfr[ni], acc[mi][ni]);
    }
    __syncthreads();
  }
  #pragma unroll
  for (int mi = 0; mi < 4; ++mi) {
    #pragma unroll
    for (int r = 0; r < 4; ++r) {
      int grow = bm * 128 + wr * 64 + mi * 16 + lg * 4 + r;
      if (EPI == 0) {
        u32 w = ((u32)grow * 48914u) >> 24; int n = grow - (int)w * 343;
        #pragma unroll
        for (int ni = 0; ni < 4; ++ni) {
          int gcol = bn * 128 + wc * 64 + ni * 16 + lr;
          float v = acc[mi][ni][r] + bias[gcol];
          if (gcol < 192) {
            int hh = gcol >> 5, d = gcol & 31;
            int dswz = ((((d >> 3) ^ ((n >> 1) & 3)) << 3) | (d & 7));
            outa[(size_t)(((int)w * 6 + hh) * NPAD + n) * 32 + dswz] = f2b(v);
          } else {
            int c2 = gcol - 192; int hh = c2 >> 5, d = c2 & 31;
            int nswz = ((((n >> 3) ^ ((d >> 1) & 3)) << 3) | (n & 7));
            outb[(size_t)(((int)w * 6 + hh) * 32 + d) * VTS + nswz] = f2b(v);
          }
        }
      } else if (EPI == 1) {
        #pragma unroll
        for (int ni = 0; ni < 4; ++ni) {
          int gcol = bn * 128 + wc * 64 + ni * 16 + lr;
          if (gcol < 192) {
            float v = acc[mi][ni][r] + bias[gcol] + xin[(size_t)grow * 192 + gcol];
            xres[(size_t)grow * 192 + gcol] = v;
          }
        }
      } else if (EPI == 2) {
        #pragma unroll
        for (int ni = 0; ni < 4; ++ni) {
          int gcol = bn * 128 + wc * 64 + ni * 16 + lr;
          float v = acc[mi][ni][r] + bias[gcol];
          v = 0.5f * v * (1.f + erff(v * 0.7071067811865476f));
          outa[(size_t)grow * 768 + gcol] = f2b(v);
        }
      } else {
        #pragma unroll
        for (int ni = 0; ni < 4; ++ni) {
          int gcol = bn * 128 + wc * 64 + ni * 16 + lr;
          if (gcol < 192)
            outf[(size_t)grow * 192 + gcol] = acc[mi][ni][r] + bias[gcol] + xin[(size_t)grow * 192 + gcol];
        }
      }
    }
  }
}

// TWO-ROW-TILE interleaved attention chunk (T15-style ILP): chains A (tile 2p) and
// B (tile 2p+1) share every K-fragment and V-fragment load; all other state is
// independent. Online softmax in exp2 domain with deferred max; ROW BOOKKEEPING as
// before (o rows are lg*4+r -> factors transposed via __shfl within each chain).
template<int CT0, int LEN, bool TAIL, bool FIRST>
__device__ __forceinline__ void attn_chunk2(const u16* __restrict__ Ks, const u16* __restrict__ Vs,
    bf16x8 qaA, bf16x8 qaB, int lr, int lg, int swz,
    const u16* __restrict__ browA, const u16* __restrict__ mrowA,
    const u16* __restrict__ browB, const u16* __restrict__ mrowB,
    f32x4& o0A, f32x4& o1A, f32x4& o0B, f32x4& o1B,
    float& mrunA, float& mrunB, float& sumA, float& sumB) {
  // issue bias+mask loads first (independent of the MFMA clusters below)
  u16x4 bbA[LEN], mmA[LEN], bbB[LEN], mmB[LEN];
  #pragma unroll
  for (int j = 0; j < LEN; ++j) {
    bbA[j] = *(const u16x4*)&browA[(CT0 + j) * 16];
    mmA[j] = *(const u16x4*)&mrowA[(CT0 + j) * 16];
    bbB[j] = *(const u16x4*)&browB[(CT0 + j) * 16];
    mmB[j] = *(const u16x4*)&mrowB[(CT0 + j) * 16];
  }
  f32x4 sA[LEN], sB[LEN];
  const f32x4 z = {0.f, 0.f, 0.f, 0.f};
  // QK^T with C=0: each kf load feeds BOTH chains
  __builtin_amdgcn_s_setprio(1);
  #pragma unroll
  for (int j = 0; j < LEN; ++j) {
    bf16x8 kf = *(const bf16x8*)&Ks[((CT0 + j) * 16 + lr) * 32 + (lg ^ swz) * 8];
    sA[j] = mfma16(kf, qaA, z);
    sB[j] = mfma16(kf, qaB, z);
  }
  __builtin_amdgcn_s_setprio(0);
  // fold bias + mask (pre-scaled by LOG2E)
  #pragma unroll
  for (int j = 0; j < LEN; ++j)
    #pragma unroll
    for (int r = 0; r < 4; ++r) {
      sA[j][r] += b2f(bbA[j][r]) + b2f(mmA[j][r]);
      sB[j][r] += b2f(bbB[j][r]) + b2f(mmB[j][r]);
    }
  if (TAIL) {   // key-dim tail (keys 336..351): applies to BOTH chains
    int m0 = 336 + lg * 4;
    #pragma unroll
    for (int r = 0; r < 4; ++r)
      if (m0 + r >= 343) { sA[LEN - 1][r] = -1e30f; sB[LEN - 1][r] = -1e30f; }
  }
  // local max per chain (row lr)
  float mlA = -1e30f, mlB = -1e30f;
  #pragma unroll
  for (int j = 0; j < LEN; ++j) {
    mlA = fmaxf(mlA, fmaxf(fmaxf(sA[j][0], sA[j][1]), fmaxf(sA[j][2], sA[j][3])));
    mlB = fmaxf(mlB, fmaxf(fmaxf(sB[j][0], sB[j][1]), fmaxf(sB[j][2], sB[j][3])));
  }
  if (FIRST) {
    mlA = fmaxf(mlA, __shfl_xor(mlA, 16)); mlA = fmaxf(mlA, __shfl_xor(mlA, 32));
    mlB = fmaxf(mlB, __shfl_xor(mlB, 16)); mlB = fmaxf(mlB, __shfl_xor(mlB, 32));
    mrunA = mlA; mrunB = mlB;
  } else {
    if (!__all(mlA <= mrunA + RESCALE_THR)) {
      mlA = fmaxf(mlA, __shfl_xor(mlA, 16)); mlA = fmaxf(mlA, __shfl_xor(mlA, 32));
      float mnew = fmaxf(mrunA, mlA);
      float sc = fexp2(mrunA - mnew);
      #pragma unroll
      for (int r = 0; r < 4; ++r) {
        float scr = __shfl(sc, lg * 4 + r);
        o0A[r] *= scr; o1A[r] *= scr;
      }
      sumA *= sc; mrunA = mnew;
    }
    if (!__all(mlB <= mrunB + RESCALE_THR)) {
      mlB = fmaxf(mlB, __shfl_xor(mlB, 16)); mlB = fmaxf(mlB, __shfl_xor(mlB, 32));
      float mnew = fmaxf(mrunB, mlB);
      float sc = fexp2(mrunB - mnew);
      #pragma unroll
      for (int r = 0; r < 4; ++r) {
        float scr = __shfl(sc, lg * 4 + r);
        o0B[r] *= scr; o1B[r] *= scr;
      }
      sumB *= sc; mrunB = mnew;
    }
  }
  // exp2 + lane-local sums
  #pragma unroll
  for (int j = 0; j < LEN; ++j)
    #pragma unroll
    for (int r = 0; r < 4; ++r) {
      float pA = fexp2(sA[j][r] - mrunA); sA[j][r] = pA; sumA += pA;
      float pB = fexp2(sB[j][r] - mrunB); sB[j][r] = pB; sumB += pB;
    }
  // PV accumulate: v0/v1 loads shared between chains
  __builtin_amdgcn_s_setprio(1);
  #pragma unroll
  for (int j = 0; j < LEN; ++j) {
    s16x4 paA, paB;
    #pragma unroll
    for (int r = 0; r < 4; ++r) { paA[r] = (short)f2b(sA[j][r]); paB[r] = (short)f2b(sB[j][r]); }
    int c16 = 2 * (CT0 + j) + (lg >> 1);
    int vo = ((c16 ^ swz) * 8) + (lg & 1) * 4;
    s16x4 v0 = *(const s16x4*)&Vs[lr * 352 + vo];
    s16x4 v1 = *(const s16x4*)&Vs[(16 + lr) * 352 + vo];
    o0A = mfma16x16(paA, v0, o0A);
    o1A = mfma16x16(paA, v1, o1A);
    o0B = mfma16x16(paB, v0, o0B);
    o1B = mfma16x16(paB, v1, o1B);
  }
  __builtin_amdgcn_s_setprio(0);
}

// ---- attention: 768 blocks = (xcd, w-local, h); K+V in LDS (chunk-swizzled); QK^T C=0;
//      register-P PV (16x16x16); deferred-max online softmax (exp2 domain); TWO query
//      row-tiles (2p, 2p+1) per wave iteration with shared K/V fragments (ILP x2).
//      Pairs p = wid + 4j, p <= 10 (waves 0-2: 3 pairs, wave 3: 2). Uncapped registers. ----
__global__ __launch_bounds__(256) void k_attn(const u16* __restrict__ qb, const u16* __restrict__ kb,
    const u16* __restrict__ vtb, const u16* __restrict__ bfull, const u16* __restrict__ maskbf,
    u16* __restrict__ att) {
  __shared__ __align__(16) u16 Ks[352 * 32];
  __shared__ __align__(16) u16 Vs[32 * 352];
  __shared__ __align__(16) u16 Ot[4][16][40];
  int bid = blockIdx.x;
  int xcd = bid & 7, i = bid >> 3;
  int wl = i / 6, h = i - wl * 6;
  int w = xcd * 16 + wl;
  int tid = threadIdx.x, wid = tid >> 6, lane = tid & 63, lr = lane & 15, lg = lane >> 4;
  const u16* Q  = qb  + (size_t)(w * 6 + h) * NPAD * 32;
  const u16* Kg = kb  + (size_t)(w * 6 + h) * NPAD * 32;
  const u16* Vg = vtb + (size_t)(w * 6 + h) * 32 * VTS;
  const u16* Bp = bfull + (size_t)h * 352 * 352;
  const u16* Mp = maskbf + (size_t)w * 352 * 352;
  #pragma unroll
  for (int it = 0; it < 11; ++it) {
    int idx = it * 256 + tid;
    if (idx < 1408) gl_lds16(Kg + idx * 8, &Ks[idx * 8]);
    else            gl_lds16(Vg + (idx - 1408) * 8, &Vs[(idx - 1408) * 8]);
  }
  __syncthreads();
  int swz = (lr >> 1) & 3;
  for (int p = wid; p <= 10; p += 4) {
    int nA = (2 * p) * 16 + lr;           // always < 343 (max tile 20 -> 335)
    int nB = nA + 16;                     // tile 2p+1; junk rows only when 2p+1 == 21
    bf16x8 qaA = *(const bf16x8*)&Q[(size_t)nA * 32 + lg * 8];
    bf16x8 qaB = *(const bf16x8*)&Q[(size_t)nB * 32 + lg * 8];
    const u16* browA = Bp + (size_t)nA * 352 + lg * 4;
    const u16* mrowA = Mp + (size_t)nA * 352 + lg * 4;
    const u16* browB = Bp + (size_t)nB * 352 + lg * 4;
    const u16* mrowB = Mp + (size_t)nB * 352 + lg * 4;
    f32x4 o0A = {0.f,0.f,0.f,0.f}, o1A = {0.f,0.f,0.f,0.f};
    f32x4 o0B = {0.f,0.f,0.f,0.f}, o1B = {0.f,0.f,0.f,0.f};
    float mrunA = -1e30f, mrunB = -1e30f, sumA = 0.f, sumB = 0.f;
    attn_chunk2<0,  6, false, true >(Ks, Vs, qaA, qaB, lr, lg, swz, browA, mrowA, browB, mrowB,
                                     o0A, o1A, o0B, o1B, mrunA, mrunB, sumA, sumB);
    attn_chunk2<6,  6, false, false>(Ks, Vs, qaA, qaB, lr, lg, swz, browA, mrowA, browB, mrowB,
                                     o0A, o1A, o0B, o1B, mrunA, mrunB, sumA, sumB);
    attn_chunk2<12, 6, false, false>(Ks, Vs, qaA, qaB, lr, lg, swz, browA, mrowA, browB, mrowB,
                                     o0A, o1A, o0B, o1B, mrunA, mrunB, sumA, sumB);
    attn_chunk2<18, 4, true,  false>(Ks, Vs, qaA, qaB, lr, lg, swz, browA, mrowA, browB, mrowB,
                                     o0A, o1A, o0B, o1B, mrunA, mrunB, sumA, sumB);
    // chain A: reduce, normalize (row-transposed), transpose through Ot, store
    sumA += __shfl_xor(sumA, 16);
    sumA += __shfl_xor(sumA, 32);
    float rsA = 1.f / sumA;
    #pragma unroll
    for (int r = 0; r < 4; ++r) {
      float rsr = __shfl(rsA, lg * 4 + r);
      Ot[wid][lg * 4 + r][lr] = f2b(o0A[r] * rsr);
      Ot[wid][lg * 4 + r][16 + lr] = f2b(o1A[r] * rsr);
    }
    {
      int g = win_to_global(w, nA);
      bf16x8 ov = *(const bf16x8*)&Ot[wid][lr][lg * 8];
      *(bf16x8*)&att[(size_t)g * 192 + h * 32 + lg * 8] = ov;
    }
    // chain B
    sumB += __shfl_xor(sumB, 16);
    sumB += __shfl_xor(sumB, 32);
    float rsB = 1.f / sumB;
    #pragma unroll
    for (int r = 0; r < 4; ++r) {
      float rsr = __shfl(rsB, lg * 4 + r);
      Ot[wid][lg * 4 + r][lr] = f2b(o0B[r] * rsr);
      Ot[wid][lg * 4 + r][16 + lr] = f2b(o1B[r] * rsr);
    }
    if (nB < 343) {
      int g = win_to_global(w, nB);
      bf16x8 ov = *(const bf16x8*)&Ot[wid][lr][lg * 8];
      *(bf16x8*)&att[(size_t)g * 192 + h * 32 + lg * 8] = ov;
    }
  }
}

// ---- workspace layout (bytes) ----
static const size_t OFF_W    = 0;
static const size_t OFF_XRES = (size_t)1 << 20;            // f32 33.7 MB (shared with maskbf)
static const size_t OFF_MASK = OFF_XRES;                   // bf16 31.7 MB, dead before xres written
static const size_t OFF_LN2  = OFF_XRES + ((size_t)34 << 20);
static const size_t OFF_SKW  = OFF_LN2  + ((size_t)17 << 20);
static const size_t OFF_Q    = OFF_SKW  + ((size_t)17 << 20);
static const size_t OFF_K    = OFF_Q    + ((size_t)17 << 20);
static const size_t OFF_VT   = OFF_K    + ((size_t)17 << 20);
static const size_t OFF_ATT  = OFF_VT   + ((size_t)17 << 20);
static const size_t OFF_BIAS = OFF_ATT  + ((size_t)17 << 20);
static const size_t OFF_FC1  = OFF_SKW;

extern "C" void kernel_launch(void* const* d_in, const int* in_sizes, int n_in,
                              void* d_out, int out_size, void* d_ws, size_t ws_size,
                              hipStream_t stream) {
  const float* x      = (const float*)d_in[0];
  const float* mask   = (const float*)d_in[1];
  const float* skip   = (const float*)d_in[2];
  const float* xup    = (const float*)d_in[3];
  const float* n1g    = (const float*)d_in[4];
  const float* n1b    = (const float*)d_in[5];
  const float* kv_w   = (const float*)d_in[6];
  const float* kv_b   = (const float*)d_in[7];
  const float* tbl    = (const float*)d_in[8];
  const float* proj_w = (const float*)d_in[9];
  const float* proj_b = (const float*)d_in[10];
  const float* n2g    = (const float*)d_in[11];
  const float* n2b    = (const float*)d_in[12];
  const float* fc1_w  = (const float*)d_in[13];
  const float* fc1_b  = (const float*)d_in[14];
  const float* fc2_w  = (const float*)d_in[15];
  const float* fc2_b  = (const float*)d_in[16];
  char* ws = (char*)d_ws;
  u16* kvT   = (u16*)(ws + OFF_W);
  u16* projT = kvT + 384 * 192;
  u16* fc1T  = projT + 256 * 192;
  u16* fc2T  = fc1T + 768 * 192;
  float* xres = (float*)(ws + OFF_XRES);
  u16* maskbf = (u16*)(ws + OFF_MASK);
  u16* ln2o  = (u16*)(ws + OFF_LN2);
  u16* skw   = (u16*)(ws + OFF_SKW);
  u16* qb    = (u16*)(ws + OFF_Q);
  u16* kb    = (u16*)(ws + OFF_K);
  u16* vt    = (u16*)(ws + OFF_VT);
  u16* att   = (u16*)(ws + OFF_ATT);
  u16* bfull = (u16*)(ws + OFF_BIAS);
  u16* fc1o  = (u16*)(ws + OFF_FC1);
  float* outp = (float*)d_out;

  k_pre<<<dim3(PRE_GRID), dim3(256), 0, stream>>>(
      mask, maskbf, skip, xup, n1g, n1b, skw, qb,
      kv_w, proj_w, fc1_w, fc2_w, kvT, projT, fc1T, fc2T, tbl, bfull);
  k_gemm<0><<<dim3(8 * 43 * 3), dim3(256), 0, stream>>>(skw, kvT, 192, 3, kv_b, kb, vt, nullptr, nullptr, nullptr);
  k_attn<<<dim3(768), dim3(256), 0, stream>>>(qb, kb, vt, bfull, maskbf, att);
  k_gemm<1><<<dim3(8 * 43 * 2), dim3(256), 0, stream>>>(att, projT, 192, 2, proj_b, nullptr, nullptr, x, xres, nullptr);
  k_ln2<<<dim3(10976), dim3(256), 0, stream>>>(xres, n2g, n2b, ln2o);
  k_gemm<2><<<dim3(8 * 43 * 6), dim3(256), 0, stream>>>(ln2o, fc1T, 192, 6, fc1_b, fc1o, nullptr, nullptr, nullptr, nullptr);
  k_gemm<3><<<dim3(8 * 43 * 2), dim3(256), 0, stream>>>(fc1o, fc2T, 768, 2, fc2_b, nullptr, nullptr, xres, nullptr, outp);
}